// Round 5
// baseline (101.742 us; speedup 1.0000x reference)
//
#include <hip/hip_runtime.h>

#define LL 512
#define NB 128
#define NW 16     // waves per block (1024 threads)

constexpr float MAXT   = 86400.0f;
constexpr float MAXD   = 50000.0f;
constexpr float EARTH2 = 2.0f * 6367000.0f;           // 2 * EARTH
constexpr float D2R    = 0.017453292519943295f;        // pi/180
constexpr float EPSF   = 1e-12f;
constexpr float NEGV   = -1000000000.0f;

__device__ __forceinline__ float wred_sum(float v) {
    #pragma unroll
    for (int m = 32; m; m >>= 1) v += __shfl_xor(v, m, 64);
    return v;
}
__device__ __forceinline__ float wred_max(float v) {
    #pragma unroll
    for (int m = 32; m; m >>= 1) v = fmaxf(v, __shfl_xor(v, m, 64));
    return v;
}

// Pairwise (dt, ds) — pure FMA/rcp/sqrt, no libcalls.
// haversine with sin^2(d/2) = sin^2(d)/(2(1+cos d)); asin via 2-term series
// (exact to ~1e-9 below the MAXD clamp threshold).
__device__ __forceinline__ float2 pair_dtds(float t_i, float4 pi,
                                            float t_j, float4 pj) {
    float dt = fminf(fabsf(t_i - t_j), MAXT);
    float p  = pi.x * pj.x;                            // cos_lat_i * cos_lat_j
    float c1 = fmaf(pi.y, pj.y, p);                    // cos(dlat)
    float s1 = fmaf(pi.y, pj.x, -pi.x * pj.y);         // sin(dlat)
    float h1 = s1 * s1 * __builtin_amdgcn_rcpf(fmaf(2.0f, c1, 2.0f));
    float c2 = fmaf(pi.w, pj.w, pi.z * pj.z);          // cos(dlon)
    float s2 = fmaf(pi.w, pj.z, -pi.z * pj.w);         // sin(dlon)
    float h2 = s2 * s2 * __builtin_amdgcn_rcpf(fmaf(2.0f, c2, 2.0f));
    float a  = fmaf(p, h2, h1);
    float x  = __builtin_amdgcn_sqrtf(a);
    float as = x * fmaf(a, fmaf(a, 0.075f, 0.16666667f), 1.0f);
    float ds = fminf(EARTH2 * as, MAXD);
    return make_float2(dt, ds);
}

// One block per batch. Phase 0: trig table + t into LDS. Phase 1: per-row
// norms (LDS) + per-lane running batch max. Phase 2: recompute r, softmax,
// coalesced stores. r <= 2 (unit-norm rows) so exp(rmax - r) <= e^2 needs no
// shift; each masked entry contributes exp(0) = 1 to the denominator.
__global__ __launch_bounds__(1024) void k_fused(
    const float* __restrict__ t_s, const float* __restrict__ s_s,
    const int* __restrict__ val_len, float* __restrict__ out)
{
    __shared__ float4 tabs[LL];    // cos/sin lat, cos/sin lon
    __shared__ float  ts[LL];      // times
    __shared__ float2 norms[LL];   // (itn, isn) per row
    __shared__ float  wmax[NW];    // per-wave batch-max partials

    const int b    = blockIdx.x;
    const int tid  = threadIdx.x;
    const int lane = tid & 63;
    const int w    = tid >> 6;
    const int vl   = val_len[b];

    // ---- phase 0: stage batch data ----
    if (tid < LL) {
        const float* sb = s_s + (size_t)b * LL * 2;
        float lon = sb[2 * tid]     * D2R;
        float lat = sb[2 * tid + 1] * D2R;
        tabs[tid] = make_float4(cosf(lat), sinf(lat), cosf(lon), sinf(lon));
        ts[tid]   = t_s[b * LL + tid];
    }
    __syncthreads();

    // ---- phase 1: row norms + batch max (wave w owns rows w, w+NW, ...) ----
    float bmx = 0.0f;                      // r >= 0; invalid rows contribute 0
    for (int i = w; i < vl; i += NW) {
        const int n = i + 1;
        const float  t_i = ts[i];
        const float4 pi  = tabs[i];
        float dt[8], ds[8], st = 0.0f, ss = 0.0f;
        #pragma unroll
        for (int k = 0; k < 8; ++k) {
            dt[k] = 0.0f; ds[k] = 0.0f;
            if ((k << 6) < n) {            // wave-uniform chunk guard
                const int j = lane + (k << 6);
                if (j < n) {
                    float2 v = pair_dtds(t_i, pi, ts[j], tabs[j]);
                    dt[k] = v.x; ds[k] = v.y;
                    st = fmaf(v.x, v.x, st);
                    ss = fmaf(v.y, v.y, ss);
                }
            }
        }
        st = wred_sum(st);
        ss = wred_sum(ss);
        const float itn = __builtin_amdgcn_rcpf(fmaxf(__builtin_amdgcn_sqrtf(st), EPSF));
        const float isn = __builtin_amdgcn_rcpf(fmaxf(__builtin_amdgcn_sqrtf(ss), EPSF));
        if (lane == 0) norms[i] = make_float2(itn, isn);
        #pragma unroll
        for (int k = 0; k < 8; ++k)
            bmx = fmaxf(bmx, fmaf(dt[k], itn, ds[k] * isn));
    }
    bmx = wred_max(bmx);
    if (lane == 0) wmax[w] = bmx;
    __syncthreads();

    float rmx = wmax[0];                   // broadcast reads, every thread
    #pragma unroll
    for (int k = 1; k < NW; ++k) rmx = fmaxf(rmx, wmax[k]);

    // ---- phase 2: softmax + store ----
    for (int i = w; i < LL; i += NW) {
        float* orow = out + ((size_t)b * LL + i) * LL;
        if (i >= vl) {                     // fully masked row -> all -1e9
            const float4 nv = make_float4(NEGV, NEGV, NEGV, NEGV);
            float4* o4 = reinterpret_cast<float4*>(orow);
            o4[lane]      = nv;
            o4[lane + 64] = nv;
            continue;
        }
        const int n = i + 1;
        const float  t_i = ts[i];
        const float4 pi  = tabs[i];
        const float2 nn  = norms[i];
        float ev[8], s = 0.0f;
        #pragma unroll
        for (int k = 0; k < 8; ++k) {
            ev[k] = 0.0f;
            if ((k << 6) < n) {            // wave-uniform chunk guard
                const int j = lane + (k << 6);
                if (j < n) {
                    float2 v = pair_dtds(t_i, pi, ts[j], tabs[j]);
                    float e = __expf(rmx - fmaf(v.x, nn.x, v.y * nn.y));
                    ev[k] = e;
                    s += e;
                }
            }
        }
        s = wred_sum(s);
        const float inv = 1.0f / (s + (float)(LL - n));
        #pragma unroll
        for (int k = 0; k < 8; ++k) {
            const int j = lane + (k << 6);
            orow[j] = (j < n) ? ev[k] * inv : NEGV;
        }
    }
}

extern "C" void kernel_launch(void* const* d_in, const int* in_sizes, int n_in,
                              void* d_out, int out_size, void* d_ws, size_t ws_size,
                              hipStream_t stream) {
    const float* t_s     = (const float*)d_in[0];
    const float* s_s     = (const float*)d_in[1];
    const int*   val_len = (const int*)d_in[2];
    float* out = (float*)d_out;

    k_fused<<<NB, NW * 64, 0, stream>>>(t_s, s_s, val_len, out);
}

// Round 7
// 48.555 us; speedup vs baseline: 2.0954x; 2.0954x over previous
//
#include <hip/hip_runtime.h>

#define LL 512
#define NB 128

typedef float f32x4 __attribute__((ext_vector_type(4)));

constexpr float MAXT   = 86400.0f;
constexpr float MAXD   = 50000.0f;
constexpr float EARTH2 = 2.0f * 6367000.0f;           // 2 * EARTH
constexpr float D2R    = 0.017453292519943295f;        // pi/180
constexpr float EPSF   = 1e-12f;
constexpr float NEGV   = -1000000000.0f;

__device__ __forceinline__ float wred_sum(float v) {
    #pragma unroll
    for (int m = 32; m; m >>= 1) v += __shfl_xor(v, m, 64);
    return v;
}
__device__ __forceinline__ float wred_max(float v) {
    #pragma unroll
    for (int m = 32; m; m >>= 1) v = fmaxf(v, __shfl_xor(v, m, 64));
    return v;
}

// Pass 0: per-point trig table (cos/sin of lat and lon in radians).
__global__ __launch_bounds__(256) void k_table(const float* __restrict__ s_s,
                                               float4* __restrict__ tab) {
    int idx = blockIdx.x * 256 + threadIdx.x;
    float lon = s_s[2 * idx]     * D2R;
    float lat = s_s[2 * idx + 1] * D2R;
    tab[idx] = make_float4(cosf(lat), sinf(lat), cosf(lon), sinf(lon));
}

// Pairwise (dt, ds) — pure FMA/rcp/sqrt, no libcalls.
// haversine with sin^2(d/2) = sin^2(d)/(2(1+cos d)); asin via 2-term series
// (exact to ~1e-9 below the MAXD clamp threshold).
__device__ __forceinline__ float2 pair_dtds(float t_i, float4 pi,
                                            float t_j, float4 pj) {
    float dt = fminf(fabsf(t_i - t_j), MAXT);
    float p  = pi.x * pj.x;                            // cos_lat_i * cos_lat_j
    float c1 = fmaf(pi.y, pj.y, p);                    // cos(dlat)
    float s1 = fmaf(pi.y, pj.x, -pi.x * pj.y);         // sin(dlat)
    float h1 = s1 * s1 * __builtin_amdgcn_rcpf(fmaf(2.0f, c1, 2.0f));
    float c2 = fmaf(pi.w, pj.w, pi.z * pj.z);          // cos(dlon)
    float s2 = fmaf(pi.w, pj.z, -pi.z * pj.w);         // sin(dlon)
    float h2 = s2 * s2 * __builtin_amdgcn_rcpf(fmaf(2.0f, c2, 2.0f));
    float a  = fmaf(p, h2, h1);
    float x  = __builtin_amdgcn_sqrtf(a);
    float as = x * fmaf(a, fmaf(a, 0.075f, 0.16666667f), 1.0f);
    float ds = fminf(EARTH2 * as, MAXD);
    return make_float2(dt, ds);
}

// Pass 1: one wave per row. Valid rows: inverse L2 norms + row max of r.
// Invalid rows (no pass1 dependency): write the constant NEGV output row NOW,
// overlapping ~half the output write with pass1 compute. Nontemporal stores
// keep tab/t_s/rowmax L2-resident for pass2.
__global__ __launch_bounds__(256) void k_pass1(
    const float* __restrict__ t_s, const float4* __restrict__ tab,
    const int* __restrict__ val_len,
    float2* __restrict__ w_norm, float* __restrict__ w_rowmax,
    float* __restrict__ out)
{
    const int tid  = threadIdx.x;
    const int lane = tid & 63;
    const int row  = blockIdx.x * 4 + (tid >> 6);
    const int b = row >> 9;
    const int i = row & (LL - 1);

    if (i >= val_len[b]) {                 // constant row: write it here
        if (lane == 0) w_rowmax[row] = 0.0f;   // neutral for batch max (r>=0)
        f32x4* o4 = reinterpret_cast<f32x4*>(out + (size_t)row * LL);
        const f32x4 nv = {NEGV, NEGV, NEGV, NEGV};
        __builtin_nontemporal_store(nv, &o4[lane]);
        __builtin_nontemporal_store(nv, &o4[lane + 64]);
        return;
    }
    const int n = i + 1;
    const float*  tb = t_s + b * LL;
    const float4* pb = tab + b * LL;
    const float  t_i = tb[i];
    const float4 pi  = pb[i];

    float dt[8], ds[8];
    float st = 0.0f, ss = 0.0f;
    #pragma unroll
    for (int k = 0; k < 8; ++k) {
        dt[k] = 0.0f; ds[k] = 0.0f;
        if ((k << 6) < n) {                // wave-uniform chunk guard
            const int j = lane + (k << 6);
            if (j < n) {
                float2 v = pair_dtds(t_i, pi, tb[j], pb[j]);
                dt[k] = v.x; ds[k] = v.y;
                st = fmaf(v.x, v.x, st);
                ss = fmaf(v.y, v.y, ss);
            }
        }
    }
    st = wred_sum(st);
    ss = wred_sum(ss);
    const float itn = __builtin_amdgcn_rcpf(fmaxf(__builtin_amdgcn_sqrtf(st), EPSF));
    const float isn = __builtin_amdgcn_rcpf(fmaxf(__builtin_amdgcn_sqrtf(ss), EPSF));

    float mx = 0.0f;
    #pragma unroll
    for (int k = 0; k < 8; ++k) mx = fmaxf(mx, fmaf(dt[k], itn, ds[k] * isn));
    mx = wred_max(mx);
    if (lane == 0) {
        w_norm[row]   = make_float2(itn, isn);
        w_rowmax[row] = mx;
    }
}

// Pass 2: valid rows only — fused per-batch max reduce (L2-resident loads),
// recompute r, softmax, coalesced nontemporal stores. r <= 2 (unit-norm rows)
// so exp(rmax - r) <= e^2 needs no shift; each masked entry contributes
// exp(0) = 1 to the denominator, added analytically.
__global__ __launch_bounds__(256) void k_pass2(
    const float* __restrict__ t_s, const float4* __restrict__ tab,
    const int* __restrict__ val_len,
    const float2* __restrict__ w_norm, const float* __restrict__ w_rowmax,
    float* __restrict__ out)
{
    const int tid  = threadIdx.x;
    const int lane = tid & 63;
    const int row  = blockIdx.x * 4 + (tid >> 6);
    const int b = row >> 9;
    const int i = row & (LL - 1);
    if (i >= val_len[b]) return;           // written by pass1
    const int n = i + 1;
    float* orow = out + (size_t)row * LL;

    // per-batch max of r (rowmax array is L2-resident; wave max-reduce)
    const float* rm = w_rowmax + (b << 9);
    float bm = fmaxf(rm[lane], rm[lane + 64]);
    #pragma unroll
    for (int k = 2; k < 8; ++k) bm = fmaxf(bm, rm[lane + (k << 6)]);
    const float rmx = wred_max(bm);

    const float*  tb = t_s + b * LL;
    const float4* pb = tab + b * LL;
    const float  t_i = tb[i];
    const float4 pi  = pb[i];
    const float2 nn  = w_norm[row];

    float ev[8];
    float s = 0.0f;
    #pragma unroll
    for (int k = 0; k < 8; ++k) {
        ev[k] = 0.0f;
        if ((k << 6) < n) {                // wave-uniform chunk guard
            const int j = lane + (k << 6);
            if (j < n) {
                float2 v = pair_dtds(t_i, pi, tb[j], pb[j]);
                float e = __expf(rmx - fmaf(v.x, nn.x, v.y * nn.y));
                ev[k] = e;
                s += e;
            }
        }
    }
    s = wred_sum(s);
    const float inv = 1.0f / (s + (float)(LL - n));

    #pragma unroll
    for (int k = 0; k < 8; ++k) {
        const int j = lane + (k << 6);
        const float o = (j < n) ? ev[k] * inv : NEGV;
        __builtin_nontemporal_store(o, &orow[j]);
    }
}

extern "C" void kernel_launch(void* const* d_in, const int* in_sizes, int n_in,
                              void* d_out, int out_size, void* d_ws, size_t ws_size,
                              hipStream_t stream) {
    const float* t_s     = (const float*)d_in[0];
    const float* s_s     = (const float*)d_in[1];
    const int*   val_len = (const int*)d_in[2];
    float* out = (float*)d_out;

    char* ws = (char*)d_ws;
    float4* tab      = (float4*)ws;                                  // 1 MB
    float2* w_norm   = (float2*)(ws + (size_t)NB * LL * 16);         // 512 KB
    float*  w_rowmax = (float*) (ws + (size_t)NB * LL * 24);         // 256 KB

    k_table<<<NB * LL / 256, 256, 0, stream>>>(s_s, tab);
    k_pass1<<<NB * LL / 4, 256, 0, stream>>>(t_s, tab, val_len, w_norm, w_rowmax, out);
    k_pass2<<<NB * LL / 4, 256, 0, stream>>>(t_s, tab, val_len, w_norm, w_rowmax, out);
}